// Round 13
// baseline (1064.498 us; speedup 1.0000x reference)
//
#include <hip/hip_runtime.h>
#include <hip/hip_bf16.h>

#define B_ 32
#define S_ 512
#define IN_ 19
#define DE_ 256
#define DD_ 128
#define HE_ 8
#define HD_ 4
#define LE_ 6
#define LD_ 2
#define FE_ 1024
#define FD_ 512
#define DH_ 32
#define BS_ (B_ * S_)

typedef __attribute__((ext_vector_type(8))) short short8;
typedef __attribute__((ext_vector_type(4))) float f32x4;

__device__ __forceinline__ short f2bf(float f) {
    union { float f; unsigned u; } x; x.f = f;
    unsigned r = x.u + 0x7fff + ((x.u >> 16) & 1);
    return (short)(r >> 16);
}
__device__ __forceinline__ float bf2f(short s) {
    union { unsigned u; float f; } x; x.u = ((unsigned)(unsigned short)s) << 16;
    return x.f;
}

#define GLL16(g, l) __builtin_amdgcn_global_load_lds( \
    (const __attribute__((address_space(1))) void*)(g), \
    (__attribute__((address_space(3))) void*)(l), 16, 0, 0)

// (1/sqrt(32)) * log2(e), folded into Q at the QKV epilogue
#define QSCALE 0.2550653169f

// ws layout byte offsets
#define WB_OFF    262144
#define STATS_OFF 10551296
#define ACT_OFF   12648448
#define STATS_FLOATS (16 * BS_ * 2)

// ---------------------------------------------------------------------------
// weight fp32 -> bf16 conversion + zero the 16 LN-stats buffers
// ---------------------------------------------------------------------------
#define NCONV 9
struct ConvTab {
    const float* src[NCONV];
    short* dst[NCONV];
    int len[NCONV];
};
__global__ __launch_bounds__(256) void conv_kernel(ConvTab tab, int total, float* statsBase) {
    int i = blockIdx.x * 256 + threadIdx.x;
    if (i < total) {
        int j = i;
        for (int e = 0; e < NCONV; ++e) {
            if (j < tab.len[e]) { tab.dst[e][j] = f2bf(tab.src[e][j]); return; }
            j -= tab.len[e];
        }
    } else if (i < total + STATS_FLOATS) {
        statsBase[i - total] = 0.f;
    }
}

// ---------------------------------------------------------------------------
// plan: packed dual scan (visible-count + am-length), one 512-thr block/batch
// ---------------------------------------------------------------------------
__global__ __launch_bounds__(S_) void plan_kernel(
    const int* __restrict__ am, const int* __restrict__ pm,
    int* __restrict__ counts, int* __restrict__ lengths, int* __restrict__ order,
    int* __restrict__ visible, int* __restrict__ idx) {
    int b = blockIdx.x, s = threadIdx.x;
    __shared__ int sc[S_];
    int a = (am[b * S_ + s] != 0);
    int v = a && (pm[b * S_ + s] == 0);
    visible[b * S_ + s] = v;
    sc[s] = v | (a << 16);
    __syncthreads();
#pragma unroll
    for (int off = 1; off < S_; off <<= 1) {
        int t = (s >= off) ? sc[s - off] : 0;
        __syncthreads();
        sc[s] += t;
        __syncthreads();
    }
    int incl = sc[s] & 0xffff;
    int tot = sc[S_ - 1];
    int total = tot & 0xffff;
    if (s == 0) { counts[b] = total; lengths[b] = tot >> 16; }
    idx[b * S_ + s] = (incl > 0) ? incl - 1 : 0;
    if (v) order[b * S_ + incl - 1] = s;
    else   order[b * S_ + total + (s - incl)] = s;
}

// ---------------------------------------------------------------------------
// encoder embed (writes RAW x0; layer-0 consumers use identity LN)
// ---------------------------------------------------------------------------
__global__ __launch_bounds__(DE_) void enc_embed_kernel(
    const float* __restrict__ ev, const float* __restrict__ w, const float* __restrict__ bias,
    const int* __restrict__ counts, const int* __restrict__ order, short* __restrict__ out) {
    int bs = blockIdx.x;
    int b = bs / S_, s = bs % S_;
    int d = threadIdx.x;
    __shared__ float e[IN_];
    bool padded = (s >= counts[b]);
    int src = order[bs];
    if (threadIdx.x < IN_)
        e[threadIdx.x] = padded ? 0.f : ev[(size_t)(b * S_ + src) * IN_ + threadIdx.x];
    __syncthreads();
    float acc = bias[d];
#pragma unroll
    for (int i = 0; i < IN_; ++i) acc += e[i] * w[d * IN_ + i];
    out[(size_t)bs * DE_ + d] = padded ? f2bf(0.f) : f2bf(acc);
}

// ---------------------------------------------------------------------------
// MFMA bf16 GEMM, 64x64 tile, BK=32, lazy-LN:
//  LNA:    apply LN(statsA, gA, beA) to A on load (manual ds_write staging;
//          LN dim = K). statsA hold (sum, sumsq) of raw rows.
//  RESOUT: epilogue computes x_new = apply(statsR,gR,beR)(C_old) + acc + bias
//          (identity if statsR==null), writes x_new raw into C, and emits
//          per-row (sum,sumsq) partials into statsOut via atomicAdd (dim = N).
//  QKV:    scatter epilogue (Q pre-scaled, K row-major, V^T).
// ---------------------------------------------------------------------------
template <bool RELU, bool QKV, bool LNA, bool RESOUT>
__global__ __launch_bounds__(256) void gemm_mfma(
    const short* __restrict__ A, const short* __restrict__ Wt, const float* __restrict__ bias,
    short* __restrict__ C, int M, int N, int K,
    short* __restrict__ qb, short* __restrict__ kb, short* __restrict__ vtb, int H, int D,
    const int* __restrict__ live,
    const float* __restrict__ statsA, const float* __restrict__ gA, const float* __restrict__ beA,
    const float* __restrict__ statsR, const float* __restrict__ gR, const float* __restrict__ beR,
    float* __restrict__ statsOut) {
    int bm = blockIdx.y * 64, bn = blockIdx.x * 64;
    if (live && (bm & (S_ - 1)) >= live[bm >> 9]) return;   // dead encoder tile
    __shared__ short As[64][32];
    __shared__ short Bs[64][32];
    int t = threadIdx.x;
    int wave = t >> 6, lane = t & 63;
    int wm = (wave >> 1) * 32, wn = (wave & 1) * 32;
    int c = lane & 15, quad = lane >> 4;
    f32x4 acc[2][2];
#pragma unroll
    for (int i = 0; i < 2; ++i)
#pragma unroll
        for (int j = 0; j < 2; ++j) acc[i][j] = (f32x4){0.f, 0.f, 0.f, 0.f};

    int srow = lane >> 2, scol = (lane & 3) * 8;
    const short* gAp = A + (size_t)(bm + wave * 16 + srow) * K + scol;
    const short* gBp = Wt + (size_t)(bn + wave * 16 + srow) * K + scol;

    float mA = 0.f, rA = 0.f;
    if (LNA) {
        int grow = bm + wave * 16 + srow;
        float s = statsA[grow * 2], sq = statsA[grow * 2 + 1];
        mA = s / K;
        rA = rsqrtf(sq / K - mA * mA + 1e-5f);
    }

    for (int k0 = 0; k0 < K; k0 += 32) {
        if (LNA) {
            short8 raw = *(const short8*)(gAp + k0);
            const float* gc = gA + k0 + scol;
            const float* bc = beA + k0 + scol;
            short8 ov;
#pragma unroll
            for (int j = 0; j < 8; ++j)
                ov[j] = f2bf((bf2f(raw[j]) - mA) * rA * gc[j] + bc[j]);
            *(short8*)&As[wave * 16 + srow][scol] = ov;
        } else {
            GLL16(gAp + k0, &As[wave * 16][0]);
        }
        GLL16(gBp + k0, &Bs[wave * 16][0]);
        __syncthreads();
        short8 a0 = *(const short8*)&As[wm + c][quad * 8];
        short8 a1 = *(const short8*)&As[wm + 16 + c][quad * 8];
        short8 b0 = *(const short8*)&Bs[wn + c][quad * 8];
        short8 b1 = *(const short8*)&Bs[wn + 16 + c][quad * 8];
        acc[0][0] = __builtin_amdgcn_mfma_f32_16x16x32_bf16(a0, b0, acc[0][0], 0, 0, 0);
        acc[0][1] = __builtin_amdgcn_mfma_f32_16x16x32_bf16(a0, b1, acc[0][1], 0, 0, 0);
        acc[1][0] = __builtin_amdgcn_mfma_f32_16x16x32_bf16(a1, b0, acc[1][0], 0, 0, 0);
        acc[1][1] = __builtin_amdgcn_mfma_f32_16x16x32_bf16(a1, b1, acc[1][1], 0, 0, 0);
        __syncthreads();
    }
#pragma unroll
    for (int mt = 0; mt < 2; ++mt)
#pragma unroll
        for (int r = 0; r < 4; ++r) {
            int R = bm + wm + mt * 16 + quad * 4 + r;
            float mR = 0.f, rR = 0.f;
            if (RESOUT && statsR) {
                float s = statsR[R * 2], sq = statsR[R * 2 + 1];
                mR = s / N;
                rR = rsqrtf(sq / N - mR * mR + 1e-5f);
            }
            float rowsum = 0.f, rowsq = 0.f;
#pragma unroll
            for (int nt = 0; nt < 2; ++nt) {
                int Ncol = bn + wn + nt * 16 + c;
                float v = acc[mt][nt][r] + (bias ? bias[Ncol] : 0.f);
                if (RELU) v = fmaxf(v, 0.f);
                if (QKV) {
                    int s = R & (S_ - 1), b2 = R >> 9;
                    if (Ncol < D) {
                        int h = Ncol >> 5, d = Ncol & 31;
                        qb[(((size_t)b2 * H + h) * S_ + s) * DH_ + d] = f2bf(v * QSCALE);
                    } else if (Ncol < 2 * D) {
                        int n2 = Ncol - D, h = n2 >> 5, d = n2 & 31;
                        kb[(((size_t)b2 * H + h) * S_ + s) * DH_ + d] = f2bf(v);
                    } else {
                        int n2 = Ncol - 2 * D, h = n2 >> 5, d = n2 & 31;
                        vtb[(((size_t)b2 * H + h) * DH_ + d) * S_ + s] = f2bf(v);
                    }
                } else if (RESOUT) {
                    short old = C[(size_t)R * N + Ncol];
                    float res = statsR ? (bf2f(old) - mR) * rR * gR[Ncol] + beR[Ncol]
                                       : bf2f(old);
                    float xv = v + res;
                    short xb = f2bf(xv);
                    C[(size_t)R * N + Ncol] = xb;
                    float xr = bf2f(xb);
                    rowsum += xr;
                    rowsq += xr * xr;
                } else {
                    C[(size_t)R * N + Ncol] = f2bf(v);
                }
            }
            if (RESOUT) {
                rowsum += __shfl_xor(rowsum, 1); rowsq += __shfl_xor(rowsq, 1);
                rowsum += __shfl_xor(rowsum, 2); rowsq += __shfl_xor(rowsq, 2);
                rowsum += __shfl_xor(rowsum, 4); rowsq += __shfl_xor(rowsq, 4);
                rowsum += __shfl_xor(rowsum, 8); rowsq += __shfl_xor(rowsq, 8);
                if (c == 0) {
                    atomicAdd(&statsOut[R * 2], rowsum);
                    atomicAdd(&statsOut[R * 2 + 1], rowsq);
                }
            }
        }
}

// ---------------------------------------------------------------------------
// Flash MFMA attention, prefix-mask chunk skipping; optional q-tile skipping.
// ---------------------------------------------------------------------------
__global__ __launch_bounds__(256) void attn_flash(
    const short* __restrict__ qb, const short* __restrict__ kb, const short* __restrict__ vtb,
    const int* __restrict__ limit_arr, const int* __restrict__ qlim,
    short* __restrict__ o, int H, int D) {
    int b = blockIdx.z, h = blockIdx.y;
    if (qlim && (int)(blockIdx.x * 64) >= qlim[b]) return;
    int wave = threadIdx.x >> 6, lane = threadIdx.x & 63;
    int q0 = blockIdx.x * 64 + wave * 16;
    int c = lane & 15, quad = lane >> 4;
    size_t bh = (size_t)b * H + h;
    __shared__ short PtAll[4][16][132];
    short (*Pt)[132] = PtAll[wave];

    f32x4 zero = (f32x4){0.f, 0.f, 0.f, 0.f};
    short8 aq = *(const short8*)&qb[(bh * S_ + q0 + c) * DH_ + quad * 8];
    const short* kbase = kb + bh * S_ * DH_;
    const short* vbase = vtb + bh * DH_ * S_;

    int limit = limit_arr[b];
    int nchunks = (limit + 127) >> 7;

    float lrow[4] = {0.f, 0.f, 0.f, 0.f};
    f32x4 o0 = zero, o1 = zero;

    for (int kc = 0; kc < nchunks; ++kc) {
        f32x4 s[8];
#pragma unroll
        for (int nt = 0; nt < 8; ++nt) {
            short8 bk = *(const short8*)&kbase[(size_t)(kc * 128 + nt * 16 + c) * DH_ + quad * 8];
            s[nt] = __builtin_amdgcn_mfma_f32_16x16x32_bf16(aq, bk, zero, 0, 0, 0);
        }
#pragma unroll
        for (int nt = 0; nt < 8; ++nt) {
            bool ok = (kc * 128 + nt * 16 + c) < limit;
#pragma unroll
            for (int r = 0; r < 4; ++r) {
                float p = ok ? exp2f(s[nt][r]) : 0.f;
                s[nt][r] = p;
                lrow[r] += p;
            }
        }
#pragma unroll
        for (int nt = 0; nt < 8; ++nt)
#pragma unroll
            for (int r = 0; r < 4; ++r)
                Pt[quad * 4 + r][nt * 16 + c] = f2bf(s[nt][r]);
        // no barrier: Pt is wave-private, intra-wave ds ordering via lgkmcnt
#pragma unroll
        for (int kk = 0; kk < 4; ++kk) {
            short8 ap = *(const short8*)&Pt[c][kk * 32 + quad * 8];
            short8 b0 = *(const short8*)&vbase[(size_t)c * S_ + kc * 128 + kk * 32 + quad * 8];
            short8 b1 = *(const short8*)&vbase[(size_t)(16 + c) * S_ + kc * 128 + kk * 32 + quad * 8];
            o0 = __builtin_amdgcn_mfma_f32_16x16x32_bf16(ap, b0, o0, 0, 0, 0);
            o1 = __builtin_amdgcn_mfma_f32_16x16x32_bf16(ap, b1, o1, 0, 0, 0);
        }
    }
#pragma unroll
    for (int r = 0; r < 4; ++r) {
        float l = lrow[r];
        l += __shfl_xor(l, 1);
        l += __shfl_xor(l, 2);
        l += __shfl_xor(l, 4);
        l += __shfl_xor(l, 8);
        float inv = 1.f / l;
        int row = quad * 4 + r;
        size_t base = (size_t)(b * S_ + q0 + row) * D + h * DH_;
        o[base + c] = f2bf(o0[r] * inv);
        o[base + 16 + c] = f2bf(o1[r] * inv);
    }
}

// ---------------------------------------------------------------------------
// decoder embed (bt raw -> bx raw)
// ---------------------------------------------------------------------------
__global__ __launch_bounds__(DD_) void dec_embed_kernel(
    const short* __restrict__ dec_vis, const float* __restrict__ mask_token,
    const int* __restrict__ visible, const int* __restrict__ idx, short* __restrict__ out) {
    int bs = blockIdx.x, d = threadIdx.x;
    int b = bs / S_;
    short val = visible[bs] ? dec_vis[(size_t)(b * S_ + idx[bs]) * DD_ + d]
                            : f2bf(mask_token[d]);
    out[(size_t)bs * DD_ + d] = val;
}

// ---------------------------------------------------------------------------
// heads: apply final LN lazily from stats, then the two 1-wide dots
// ---------------------------------------------------------------------------
__global__ __launch_bounds__(64) void head_kernel(
    const short* __restrict__ x, const float* __restrict__ stats,
    const float* __restrict__ g, const float* __restrict__ be,
    const float* __restrict__ qw, const float* __restrict__ qb,
    const float* __restrict__ dw, const float* __restrict__ db, float* __restrict__ out) {
    int row = blockIdx.x, t = threadIdx.x;
    float s = stats[row * 2], sq = stats[row * 2 + 1];
    float m = s / DD_;
    float r = rsqrtf(sq / DD_ - m * m + 1e-5f);
    float v0 = (bf2f(x[(size_t)row * DD_ + t]) - m) * r * g[t] + be[t];
    float v1 = (bf2f(x[(size_t)row * DD_ + 64 + t]) - m) * r * g[64 + t] + be[64 + t];
    float q = v0 * qw[t] + v1 * qw[64 + t];
    float dt = v0 * dw[t] + v1 * dw[64 + t];
#pragma unroll
    for (int off = 32; off; off >>= 1) {
        q += __shfl_xor(q, off, 64);
        dt += __shfl_xor(dt, off, 64);
    }
    if (t == 0) {
        out[(size_t)row * 2 + 0] = q + qb[0];
        out[(size_t)row * 2 + 1] = dt + db[0];
    }
}

// ---------------------------------------------------------------------------
extern "C" void kernel_launch(void* const* d_in, const int* in_sizes, int n_in,
                              void* d_out, int out_size, void* d_ws, size_t ws_size,
                              hipStream_t stream) {
    const float* ev      = (const float*)d_in[0];
    const int*  am       = (const int*)d_in[1];
    const int*  pm       = (const int*)d_in[2];
    const float* w_in    = (const float*)d_in[3];
    const float* b_in    = (const float*)d_in[4];
    const float* eqkv_w  = (const float*)d_in[5];
    const float* eqkv_b  = (const float*)d_in[6];
    const float* eout_w  = (const float*)d_in[7];
    const float* eout_b  = (const float*)d_in[8];
    const float* ef1_w   = (const float*)d_in[9];
    const float* ef1_b   = (const float*)d_in[10];
    const float* ef2_w   = (const float*)d_in[11];
    const float* ef2_b   = (const float*)d_in[12];
    const float* eg1     = (const float*)d_in[13];
    const float* eb1     = (const float*)d_in[14];
    const float* eg2     = (const float*)d_in[15];
    const float* eb2     = (const float*)d_in[16];
    const float* mask_tok= (const float*)d_in[17];
    const float* e2d_w   = (const float*)d_in[18];
    const float* dqkv_w  = (const float*)d_in[19];
    const float* dqkv_b  = (const float*)d_in[20];
    const float* dout_w  = (const float*)d_in[21];
    const float* dout_b  = (const float*)d_in[22];
    const float* df1_w   = (const float*)d_in[23];
    const float* df1_b   = (const float*)d_in[24];
    const float* df2_w   = (const float*)d_in[25];
    const float* df2_b   = (const float*)d_in[26];
    const float* dg1     = (const float*)d_in[27];
    const float* db1     = (const float*)d_in[28];
    const float* dg2     = (const float*)d_in[29];
    const float* db2     = (const float*)d_in[30];
    const float* qh_w    = (const float*)d_in[31];
    const float* qh_b    = (const float*)d_in[32];
    const float* dth_w   = (const float*)d_in[33];
    const float* dth_b   = (const float*)d_in[34];
    float* out = (float*)d_out;

    char* ws = (char*)d_ws;
    int* counts  = (int*)ws;
    int* lengths = counts + 32;
    int* order   = lengths + 32;
    int* visible = order + BS_;
    int* idx     = visible + BS_;

    short* wb = (short*)(ws + WB_OFF);
    const int L_eqkv = LE_ * 3 * DE_ * DE_;
    const int L_eout = LE_ * DE_ * DE_;
    const int L_ef1  = LE_ * FE_ * DE_;
    const int L_ef2  = LE_ * DE_ * FE_;
    const int L_e2d  = DD_ * DE_;
    const int L_dqkv = LD_ * 3 * DD_ * DD_;
    const int L_dout = LD_ * DD_ * DD_;
    const int L_df1  = LD_ * FD_ * DD_;
    const int L_df2  = LD_ * DD_ * FD_;
    short* w_eqkv = wb;
    short* w_eout = w_eqkv + L_eqkv;
    short* w_ef1  = w_eout + L_eout;
    short* w_ef2  = w_ef1 + L_ef1;
    short* w_e2d  = w_ef2 + L_ef2;
    short* w_dqkv = w_e2d + L_e2d;
    short* w_dout = w_dqkv + L_dqkv;
    short* w_df1  = w_dout + L_dout;
    short* w_df2  = w_df1 + L_df1;
    const int convTotal = L_eqkv + L_eout + L_ef1 + L_ef2 + L_e2d + L_dqkv + L_dout + L_df1 + L_df2;

    // LN stats buffers: (sum, sumsq) per row, 16 buffers
    float* stats = (float*)(ws + STATS_OFF);
    float* s1e[LE_], *s2e[LE_], *s1d[LD_], *s2d[LD_];
    for (int l = 0; l < LE_; ++l) { s1e[l] = stats + (size_t)l * BS_ * 2; s2e[l] = stats + (size_t)(6 + l) * BS_ * 2; }
    for (int l = 0; l < LD_; ++l) { s1d[l] = stats + (size_t)(12 + l) * BS_ * 2; s2d[l] = stats + (size_t)(14 + l) * BS_ * 2; }

    short* bx    = (short*)(ws + ACT_OFF);
    short* qbuf  = bx   + (size_t)BS_ * DE_;
    short* kbuf  = qbuf + (size_t)B_ * HE_ * S_ * DH_;
    short* vtbuf = kbuf + (size_t)B_ * HE_ * S_ * DH_;
    short* battn = vtbuf + (size_t)B_ * HE_ * S_ * DH_;
    short* bt    = battn + (size_t)BS_ * DE_;
    short* hid   = bt + (size_t)BS_ * DE_;

    ConvTab tab;
    tab.src[0] = eqkv_w; tab.dst[0] = w_eqkv; tab.len[0] = L_eqkv;
    tab.src[1] = eout_w; tab.dst[1] = w_eout; tab.len[1] = L_eout;
    tab.src[2] = ef1_w;  tab.dst[2] = w_ef1;  tab.len[2] = L_ef1;
    tab.src[3] = ef2_w;  tab.dst[3] = w_ef2;  tab.len[3] = L_ef2;
    tab.src[4] = e2d_w;  tab.dst[4] = w_e2d;  tab.len[4] = L_e2d;
    tab.src[5] = dqkv_w; tab.dst[5] = w_dqkv; tab.len[5] = L_dqkv;
    tab.src[6] = dout_w; tab.dst[6] = w_dout; tab.len[6] = L_dout;
    tab.src[7] = df1_w;  tab.dst[7] = w_df1;  tab.len[7] = L_df1;
    tab.src[8] = df2_w;  tab.dst[8] = w_df2;  tab.len[8] = L_df2;
    conv_kernel<<<(convTotal + STATS_FLOATS + 255) / 256, 256, 0, stream>>>(tab, convTotal, stats);

    plan_kernel<<<B_, S_, 0, stream>>>(am, pm, counts, lengths, order, visible, idx);
    enc_embed_kernel<<<BS_, DE_, 0, stream>>>(ev, w_in, b_in, counts, order, bx);

    // -------------------- encoder: 5 dispatches/layer (lazy LN) -----------
    for (int l = 0; l < LE_; ++l) {
        const float* pstats = (l > 0) ? s2e[l - 1] : nullptr;
        const float* pg = eg2 + (size_t)(l ? l - 1 : 0) * DE_;
        const float* pb = eb2 + (size_t)(l ? l - 1 : 0) * DE_;
        if (l == 0)
            gemm_mfma<false, true, false, false><<<dim3(3 * DE_ / 64, BS_ / 64), 256, 0, stream>>>(
                bx, w_eqkv + (size_t)l * 3 * DE_ * DE_, eqkv_b + (size_t)l * 3 * DE_,
                nullptr, BS_, 3 * DE_, DE_, qbuf, kbuf, vtbuf, HE_, DE_, counts,
                nullptr, nullptr, nullptr, nullptr, nullptr, nullptr, nullptr);
        else
            gemm_mfma<false, true, true, false><<<dim3(3 * DE_ / 64, BS_ / 64), 256, 0, stream>>>(
                bx, w_eqkv + (size_t)l * 3 * DE_ * DE_, eqkv_b + (size_t)l * 3 * DE_,
                nullptr, BS_, 3 * DE_, DE_, qbuf, kbuf, vtbuf, HE_, DE_, counts,
                pstats, pg, pb, nullptr, nullptr, nullptr, nullptr);
        attn_flash<<<dim3(S_ / 64, HE_, B_), 256, 0, stream>>>(
            qbuf, kbuf, vtbuf, counts, counts, battn, HE_, DE_);
        gemm_mfma<false, false, false, true><<<dim3(DE_ / 64, BS_ / 64), 256, 0, stream>>>(
            battn, w_eout + (size_t)l * DE_ * DE_, eout_b + (size_t)l * DE_,
            bx, BS_, DE_, DE_, nullptr, nullptr, nullptr, 0, 0, counts,
            nullptr, nullptr, nullptr, pstats, pg, pb, s1e[l]);
        gemm_mfma<true, false, true, false><<<dim3(FE_ / 64, BS_ / 64), 256, 0, stream>>>(
            bx, w_ef1 + (size_t)l * FE_ * DE_, ef1_b + (size_t)l * FE_,
            hid, BS_, FE_, DE_, nullptr, nullptr, nullptr, 0, 0, counts,
            s1e[l], eg1 + (size_t)l * DE_, eb1 + (size_t)l * DE_, nullptr, nullptr, nullptr, nullptr);
        gemm_mfma<false, false, false, true><<<dim3(DE_ / 64, BS_ / 64), 256, 0, stream>>>(
            hid, w_ef2 + (size_t)l * DE_ * FE_, ef2_b + (size_t)l * DE_,
            bx, BS_, DE_, FE_, nullptr, nullptr, nullptr, 0, 0, counts,
            nullptr, nullptr, nullptr, s1e[l], eg1 + (size_t)l * DE_, eb1 + (size_t)l * DE_, s2e[l]);
    }

    // -------------------- enc -> dec --------------------
    gemm_mfma<false, false, true, false><<<dim3(DD_ / 64, BS_ / 64), 256, 0, stream>>>(
        bx, w_e2d, nullptr, bt, BS_, DD_, DE_, nullptr, nullptr, nullptr, 0, 0, counts,
        s2e[LE_ - 1], eg2 + (size_t)(LE_ - 1) * DE_, eb2 + (size_t)(LE_ - 1) * DE_,
        nullptr, nullptr, nullptr, nullptr);
    dec_embed_kernel<<<BS_, DD_, 0, stream>>>(bt, mask_tok, visible, idx, bx);

    // -------------------- decoder: 5 dispatches/layer ---------------------
    for (int l = 0; l < LD_; ++l) {
        const float* pstats = (l > 0) ? s2d[l - 1] : nullptr;
        const float* pg = dg2 + (size_t)(l ? l - 1 : 0) * DD_;
        const float* pb = db2 + (size_t)(l ? l - 1 : 0) * DD_;
        if (l == 0)
            gemm_mfma<false, true, false, false><<<dim3(3 * DD_ / 64, BS_ / 64), 256, 0, stream>>>(
                bx, w_dqkv + (size_t)l * 3 * DD_ * DD_, dqkv_b + (size_t)l * 3 * DD_,
                nullptr, BS_, 3 * DD_, DD_, qbuf, kbuf, vtbuf, HD_, DD_, nullptr,
                nullptr, nullptr, nullptr, nullptr, nullptr, nullptr, nullptr);
        else
            gemm_mfma<false, true, true, false><<<dim3(3 * DD_ / 64, BS_ / 64), 256, 0, stream>>>(
                bx, w_dqkv + (size_t)l * 3 * DD_ * DD_, dqkv_b + (size_t)l * 3 * DD_,
                nullptr, BS_, 3 * DD_, DD_, qbuf, kbuf, vtbuf, HD_, DD_, nullptr,
                pstats, pg, pb, nullptr, nullptr, nullptr, nullptr);
        attn_flash<<<dim3(S_ / 64, HD_, B_), 256, 0, stream>>>(
            qbuf, kbuf, vtbuf, lengths, nullptr, battn, HD_, DD_);
        gemm_mfma<false, false, false, true><<<dim3(DD_ / 64, BS_ / 64), 256, 0, stream>>>(
            battn, w_dout + (size_t)l * DD_ * DD_, dout_b + (size_t)l * DD_,
            bx, BS_, DD_, DD_, nullptr, nullptr, nullptr, 0, 0, nullptr,
            nullptr, nullptr, nullptr, pstats, pg, pb, s1d[l]);
        gemm_mfma<true, false, true, false><<<dim3(FD_ / 64, BS_ / 64), 256, 0, stream>>>(
            bx, w_df1 + (size_t)l * FD_ * DD_, df1_b + (size_t)l * FD_,
            hid, BS_, FD_, DD_, nullptr, nullptr, nullptr, 0, 0, nullptr,
            s1d[l], dg1 + (size_t)l * DD_, db1 + (size_t)l * DD_, nullptr, nullptr, nullptr, nullptr);
        gemm_mfma<false, false, false, true><<<dim3(DD_ / 64, BS_ / 64), 256, 0, stream>>>(
            hid, w_df2 + (size_t)l * DD_ * FD_, df2_b + (size_t)l * DD_,
            bx, BS_, DD_, FD_, nullptr, nullptr, nullptr, 0, 0, nullptr,
            nullptr, nullptr, nullptr, s1d[l], dg1 + (size_t)l * DD_, db1 + (size_t)l * DD_, s2d[l]);
    }

    head_kernel<<<BS_, 64, 0, stream>>>(
        bx, s2d[LD_ - 1], dg2 + (size_t)(LD_ - 1) * DD_, db2 + (size_t)(LD_ - 1) * DD_,
        qh_w, qh_b, dth_w, dth_b, out);
}

// Round 14
// 900.796 us; speedup vs baseline: 1.1817x; 1.1817x over previous
//
#include <hip/hip_runtime.h>
#include <hip/hip_bf16.h>

#define B_ 32
#define S_ 512
#define IN_ 19
#define DE_ 256
#define DD_ 128
#define HE_ 8
#define HD_ 4
#define LE_ 6
#define LD_ 2
#define FE_ 1024
#define FD_ 512
#define DH_ 32

typedef __attribute__((ext_vector_type(8))) short short8;
typedef __attribute__((ext_vector_type(4))) float f32x4;

__device__ __forceinline__ short f2bf(float f) {
    union { float f; unsigned u; } x; x.f = f;
    unsigned r = x.u + 0x7fff + ((x.u >> 16) & 1);
    return (short)(r >> 16);
}
__device__ __forceinline__ float bf2f(short s) {
    union { unsigned u; float f; } x; x.u = ((unsigned)(unsigned short)s) << 16;
    return x.f;
}

#define GLL16(g, l) __builtin_amdgcn_global_load_lds( \
    (const __attribute__((address_space(1))) void*)(g), \
    (__attribute__((address_space(3))) void*)(l), 16, 0, 0)

// (1/sqrt(32)) * log2(e), folded into Q at the QKV epilogue
#define QSCALE 0.2550653169f

// ---------------------------------------------------------------------------
// weight fp32 -> bf16 conversion
// ---------------------------------------------------------------------------
#define NCONV 9
struct ConvTab {
    const float* src[NCONV];
    short* dst[NCONV];
    int len[NCONV];
};
__global__ __launch_bounds__(256) void conv_kernel(ConvTab tab, int total) {
    int i = blockIdx.x * 256 + threadIdx.x;
    if (i >= total) return;
    int j = i;
    for (int e = 0; e < NCONV; ++e) {
        if (j < tab.len[e]) { tab.dst[e][j] = f2bf(tab.src[e][j]); return; }
        j -= tab.len[e];
    }
}

// ---------------------------------------------------------------------------
// plan: packed dual scan (visible-count + am-length), one 512-thr block/batch
// ---------------------------------------------------------------------------
__global__ __launch_bounds__(S_) void plan_kernel(
    const int* __restrict__ am, const int* __restrict__ pm,
    int* __restrict__ counts, int* __restrict__ lengths, int* __restrict__ order,
    int* __restrict__ visible, int* __restrict__ idx) {
    int b = blockIdx.x, s = threadIdx.x;
    __shared__ int sc[S_];
    int a = (am[b * S_ + s] != 0);
    int v = a && (pm[b * S_ + s] == 0);
    visible[b * S_ + s] = v;
    sc[s] = v | (a << 16);
    __syncthreads();
#pragma unroll
    for (int off = 1; off < S_; off <<= 1) {
        int t = (s >= off) ? sc[s - off] : 0;
        __syncthreads();
        sc[s] += t;
        __syncthreads();
    }
    int incl = sc[s] & 0xffff;
    int tot = sc[S_ - 1];
    int total = tot & 0xffff;
    if (s == 0) { counts[b] = total; lengths[b] = tot >> 16; }
    idx[b * S_ + s] = (incl > 0) ? incl - 1 : 0;
    if (v) order[b * S_ + incl - 1] = s;
    else   order[b * S_ + total + (s - incl)] = s;
}

// ---------------------------------------------------------------------------
// encoder embed
// ---------------------------------------------------------------------------
__global__ __launch_bounds__(DE_) void enc_embed_kernel(
    const float* __restrict__ ev, const float* __restrict__ w, const float* __restrict__ bias,
    const int* __restrict__ counts, const int* __restrict__ order, short* __restrict__ out) {
    int bs = blockIdx.x;
    int b = bs / S_, s = bs % S_;
    int d = threadIdx.x;
    __shared__ float e[IN_];
    bool padded = (s >= counts[b]);
    int src = order[bs];
    if (threadIdx.x < IN_)
        e[threadIdx.x] = padded ? 0.f : ev[(size_t)(b * S_ + src) * IN_ + threadIdx.x];
    __syncthreads();
    float acc = bias[d];
#pragma unroll
    for (int i = 0; i < IN_; ++i) acc += e[i] * w[d * IN_ + i];
    out[(size_t)bs * DE_ + d] = padded ? f2bf(0.f) : f2bf(acc);
}

// ---------------------------------------------------------------------------
// MFMA bf16 GEMM, 64x64 tile, BK=128 via 4 slabs of the proven round-12
// [64][32] staging layout (bank-conflict-free; GLL16 lane-contiguity kept).
// Barrier pairs = K/128 (4x fewer than BK=32). MFMA order per accumulator
// unchanged (k ascending) -> bit-identical results. Requires K % 128 == 0.
// live: dead-encoder-tile skip.
// ---------------------------------------------------------------------------
template <bool RELU, bool QKV>
__global__ __launch_bounds__(256) void gemm_mfma(
    const short* __restrict__ A, const short* __restrict__ Wt, const float* __restrict__ bias,
    short* __restrict__ C, int M, int N, int K,
    short* __restrict__ qb, short* __restrict__ kb, short* __restrict__ vtb, int H, int D,
    const int* __restrict__ live) {
    int bm = blockIdx.y * 64, bn = blockIdx.x * 64;
    if (live && (bm & (S_ - 1)) >= live[bm >> 9]) return;   // dead encoder tile
    __shared__ short As[4][64][32];
    __shared__ short Bs[4][64][32];
    int t = threadIdx.x;
    int wave = t >> 6, lane = t & 63;
    int wm = (wave >> 1) * 32, wn = (wave & 1) * 32;
    int c = lane & 15, quad = lane >> 4;
    f32x4 acc[2][2];
#pragma unroll
    for (int i = 0; i < 2; ++i)
#pragma unroll
        for (int j = 0; j < 2; ++j) acc[i][j] = (f32x4){0.f, 0.f, 0.f, 0.f};

    // per-slab staging: wave stages 16 rows x 32 cols (1 KiB per GLL16)
    const short* gA = A + (size_t)(bm + wave * 16 + (lane >> 2)) * K + (lane & 3) * 8;
    const short* gB = Wt + (size_t)(bn + wave * 16 + (lane >> 2)) * K + (lane & 3) * 8;

    for (int k0 = 0; k0 < K; k0 += 128) {
#pragma unroll
        for (int j = 0; j < 4; ++j) {
            GLL16(gA + k0 + j * 32, &As[j][wave * 16][0]);
            GLL16(gB + k0 + j * 32, &Bs[j][wave * 16][0]);
        }
        __syncthreads();
#pragma unroll
        for (int j = 0; j < 4; ++j) {
            short8 a0 = *(const short8*)&As[j][wm + c][quad * 8];
            short8 a1 = *(const short8*)&As[j][wm + 16 + c][quad * 8];
            short8 b0 = *(const short8*)&Bs[j][wn + c][quad * 8];
            short8 b1 = *(const short8*)&Bs[j][wn + 16 + c][quad * 8];
            acc[0][0] = __builtin_amdgcn_mfma_f32_16x16x32_bf16(a0, b0, acc[0][0], 0, 0, 0);
            acc[0][1] = __builtin_amdgcn_mfma_f32_16x16x32_bf16(a0, b1, acc[0][1], 0, 0, 0);
            acc[1][0] = __builtin_amdgcn_mfma_f32_16x16x32_bf16(a1, b0, acc[1][0], 0, 0, 0);
            acc[1][1] = __builtin_amdgcn_mfma_f32_16x16x32_bf16(a1, b1, acc[1][1], 0, 0, 0);
        }
        __syncthreads();
    }
#pragma unroll
    for (int mt = 0; mt < 2; ++mt)
#pragma unroll
        for (int nt = 0; nt < 2; ++nt)
#pragma unroll
            for (int r = 0; r < 4; ++r) {
                int R = bm + wm + mt * 16 + quad * 4 + r;
                int Ncol = bn + wn + nt * 16 + c;
                float v = acc[mt][nt][r] + (bias ? bias[Ncol] : 0.f);
                if (RELU) v = fmaxf(v, 0.f);
                if (!QKV) {
                    C[(size_t)R * N + Ncol] = f2bf(v);
                } else {
                    int s = R & (S_ - 1), b2 = R >> 9;
                    if (Ncol < D) {
                        int h = Ncol >> 5, d = Ncol & 31;
                        qb[(((size_t)b2 * H + h) * S_ + s) * DH_ + d] = f2bf(v * QSCALE);
                    } else if (Ncol < 2 * D) {
                        int n2 = Ncol - D, h = n2 >> 5, d = n2 & 31;
                        kb[(((size_t)b2 * H + h) * S_ + s) * DH_ + d] = f2bf(v);
                    } else {
                        int n2 = Ncol - 2 * D, h = n2 >> 5, d = n2 & 31;
                        vtb[(((size_t)b2 * H + h) * DH_ + d) * S_ + s] = f2bf(v);
                    }
                }
            }
}

// ---------------------------------------------------------------------------
// Flash MFMA attention, prefix-mask chunk skipping; optional q-tile skipping.
// ---------------------------------------------------------------------------
__global__ __launch_bounds__(256) void attn_flash(
    const short* __restrict__ qb, const short* __restrict__ kb, const short* __restrict__ vtb,
    const int* __restrict__ limit_arr, const int* __restrict__ qlim,
    short* __restrict__ o, int H, int D) {
    int b = blockIdx.z, h = blockIdx.y;
    if (qlim && (int)(blockIdx.x * 64) >= qlim[b]) return;
    int wave = threadIdx.x >> 6, lane = threadIdx.x & 63;
    int q0 = blockIdx.x * 64 + wave * 16;
    int c = lane & 15, quad = lane >> 4;
    size_t bh = (size_t)b * H + h;
    __shared__ short PtAll[4][16][132];
    short (*Pt)[132] = PtAll[wave];

    f32x4 zero = (f32x4){0.f, 0.f, 0.f, 0.f};
    short8 aq = *(const short8*)&qb[(bh * S_ + q0 + c) * DH_ + quad * 8];
    const short* kbase = kb + bh * S_ * DH_;
    const short* vbase = vtb + bh * DH_ * S_;

    int limit = limit_arr[b];
    int nchunks = (limit + 127) >> 7;

    float lrow[4] = {0.f, 0.f, 0.f, 0.f};
    f32x4 o0 = zero, o1 = zero;

    for (int kc = 0; kc < nchunks; ++kc) {
        f32x4 s[8];
#pragma unroll
        for (int nt = 0; nt < 8; ++nt) {
            short8 bk = *(const short8*)&kbase[(size_t)(kc * 128 + nt * 16 + c) * DH_ + quad * 8];
            s[nt] = __builtin_amdgcn_mfma_f32_16x16x32_bf16(aq, bk, zero, 0, 0, 0);
        }
#pragma unroll
        for (int nt = 0; nt < 8; ++nt) {
            bool ok = (kc * 128 + nt * 16 + c) < limit;
#pragma unroll
            for (int r = 0; r < 4; ++r) {
                float p = ok ? exp2f(s[nt][r]) : 0.f;
                s[nt][r] = p;
                lrow[r] += p;
            }
        }
#pragma unroll
        for (int nt = 0; nt < 8; ++nt)
#pragma unroll
            for (int r = 0; r < 4; ++r)
                Pt[quad * 4 + r][nt * 16 + c] = f2bf(s[nt][r]);
        // no barrier: Pt is wave-private, intra-wave ds ordering via lgkmcnt
#pragma unroll
        for (int kk = 0; kk < 4; ++kk) {
            short8 ap = *(const short8*)&Pt[c][kk * 32 + quad * 8];
            short8 b0 = *(const short8*)&vbase[(size_t)c * S_ + kc * 128 + kk * 32 + quad * 8];
            short8 b1 = *(const short8*)&vbase[(size_t)(16 + c) * S_ + kc * 128 + kk * 32 + quad * 8];
            o0 = __builtin_amdgcn_mfma_f32_16x16x32_bf16(ap, b0, o0, 0, 0, 0);
            o1 = __builtin_amdgcn_mfma_f32_16x16x32_bf16(ap, b1, o1, 0, 0, 0);
        }
    }
#pragma unroll
    for (int r = 0; r < 4; ++r) {
        float l = lrow[r];
        l += __shfl_xor(l, 1);
        l += __shfl_xor(l, 2);
        l += __shfl_xor(l, 4);
        l += __shfl_xor(l, 8);
        float inv = 1.f / l;
        int row = quad * 4 + r;
        size_t base = (size_t)(b * S_ + q0 + row) * D + h * DH_;
        o[base + c] = f2bf(o0[r] * inv);
        o[base + 16 + c] = f2bf(o1[r] * inv);
    }
}

// ---------------------------------------------------------------------------
// out = LN(x + h) * g + b — one WAVE per row; optional dead-row skip
// ---------------------------------------------------------------------------
template <int D>
__global__ __launch_bounds__(64) void add_ln_kernel(
    const short* __restrict__ x, const short* __restrict__ h,
    const float* __restrict__ g, const float* __restrict__ be,
    short* __restrict__ out, const int* __restrict__ live) {
    constexpr int E = D / 64;
    int row = blockIdx.x, t = threadIdx.x;
    if (live && (row & (S_ - 1)) >= live[row >> 9]) return;
    const short* px = x + (size_t)row * D + t * E;
    const short* ph = h + (size_t)row * D + t * E;
    float v[E];
    float s = 0.f;
#pragma unroll
    for (int e = 0; e < E; ++e) {
        v[e] = bf2f(px[e]) + bf2f(ph[e]);
        s += v[e];
    }
#pragma unroll
    for (int off = 32; off; off >>= 1) s += __shfl_xor(s, off, 64);
    float m = s / D;
    float s2 = 0.f;
#pragma unroll
    for (int e = 0; e < E; ++e) {
        float d = v[e] - m;
        s2 += d * d;
    }
#pragma unroll
    for (int off = 32; off; off >>= 1) s2 += __shfl_xor(s2, off, 64);
    float rstd = rsqrtf(s2 / D + 1e-5f);
    short* po = out + (size_t)row * D + t * E;
#pragma unroll
    for (int e = 0; e < E; ++e)
        po[e] = f2bf((v[e] - m) * rstd * g[t * E + e] + be[t * E + e]);
}

// ---------------------------------------------------------------------------
// final decoder add_ln + heads fused (D = 128, one wave per row):
// out[row] = [ LN(x+h) . qw + qb , LN(x+h) . dw + db ]
// ---------------------------------------------------------------------------
__global__ __launch_bounds__(64) void add_ln_head_kernel(
    const short* __restrict__ x, const short* __restrict__ h,
    const float* __restrict__ g, const float* __restrict__ be,
    const float* __restrict__ qw, const float* __restrict__ qb,
    const float* __restrict__ dw, const float* __restrict__ db,
    float* __restrict__ out) {
    int row = blockIdx.x, t = threadIdx.x;
    int d0 = t * 2, d1 = t * 2 + 1;
    float v0 = bf2f(x[(size_t)row * DD_ + d0]) + bf2f(h[(size_t)row * DD_ + d0]);
    float v1 = bf2f(x[(size_t)row * DD_ + d1]) + bf2f(h[(size_t)row * DD_ + d1]);
    float s = v0 + v1;
#pragma unroll
    for (int off = 32; off; off >>= 1) s += __shfl_xor(s, off, 64);
    float m = s / DD_;
    float a0 = v0 - m, a1 = v1 - m;
    float s2 = a0 * a0 + a1 * a1;
#pragma unroll
    for (int off = 32; off; off >>= 1) s2 += __shfl_xor(s2, off, 64);
    float rstd = rsqrtf(s2 / DD_ + 1e-5f);
    float o0 = a0 * rstd * g[d0] + be[d0];
    float o1 = a1 * rstd * g[d1] + be[d1];
    float q = o0 * qw[d0] + o1 * qw[d1];
    float dt = o0 * dw[d0] + o1 * dw[d1];
#pragma unroll
    for (int off = 32; off; off >>= 1) {
        q += __shfl_xor(q, off, 64);
        dt += __shfl_xor(dt, off, 64);
    }
    if (t == 0) {
        out[(size_t)row * 2 + 0] = q + qb[0];
        out[(size_t)row * 2 + 1] = dt + db[0];
    }
}

// ---------------------------------------------------------------------------
// decoder embed
// ---------------------------------------------------------------------------
__global__ __launch_bounds__(DD_) void dec_embed_kernel(
    const short* __restrict__ dec_vis, const float* __restrict__ mask_token,
    const int* __restrict__ visible, const int* __restrict__ idx, short* __restrict__ out) {
    int bs = blockIdx.x, d = threadIdx.x;
    int b = bs / S_;
    short val = visible[bs] ? dec_vis[(size_t)(b * S_ + idx[bs]) * DD_ + d]
                            : f2bf(mask_token[d]);
    out[(size_t)bs * DD_ + d] = val;
}

// ---------------------------------------------------------------------------
extern "C" void kernel_launch(void* const* d_in, const int* in_sizes, int n_in,
                              void* d_out, int out_size, void* d_ws, size_t ws_size,
                              hipStream_t stream) {
    const float* ev      = (const float*)d_in[0];
    const int*  am       = (const int*)d_in[1];
    const int*  pm       = (const int*)d_in[2];
    const float* w_in    = (const float*)d_in[3];
    const float* b_in    = (const float*)d_in[4];
    const float* eqkv_w  = (const float*)d_in[5];
    const float* eqkv_b  = (const float*)d_in[6];
    const float* eout_w  = (const float*)d_in[7];
    const float* eout_b  = (const float*)d_in[8];
    const float* ef1_w   = (const float*)d_in[9];
    const float* ef1_b   = (const float*)d_in[10];
    const float* ef2_w   = (const float*)d_in[11];
    const float* ef2_b   = (const float*)d_in[12];
    const float* eg1     = (const float*)d_in[13];
    const float* eb1     = (const float*)d_in[14];
    const float* eg2     = (const float*)d_in[15];
    const float* eb2     = (const float*)d_in[16];
    const float* mask_tok= (const float*)d_in[17];
    const float* e2d_w   = (const float*)d_in[18];
    const float* dqkv_w  = (const float*)d_in[19];
    const float* dqkv_b  = (const float*)d_in[20];
    const float* dout_w  = (const float*)d_in[21];
    const float* dout_b  = (const float*)d_in[22];
    const float* df1_w   = (const float*)d_in[23];
    const float* df1_b   = (const float*)d_in[24];
    const float* df2_w   = (const float*)d_in[25];
    const float* df2_b   = (const float*)d_in[26];
    const float* dg1     = (const float*)d_in[27];
    const float* db1     = (const float*)d_in[28];
    const float* dg2     = (const float*)d_in[29];
    const float* db2     = (const float*)d_in[30];
    const float* qh_w    = (const float*)d_in[31];
    const float* qh_b    = (const float*)d_in[32];
    const float* dth_w   = (const float*)d_in[33];
    const float* dth_b   = (const float*)d_in[34];
    float* out = (float*)d_out;

    const int BS = B_ * S_;
    char* ws = (char*)d_ws;
    int* counts  = (int*)ws;
    int* lengths = counts + 32;
    int* order   = lengths + 32;
    int* visible = order + BS;
    int* idx     = visible + BS;

    short* wb = (short*)(ws + 256 * 1024);
    const int L_eqkv = LE_ * 3 * DE_ * DE_;
    const int L_eout = LE_ * DE_ * DE_;
    const int L_ef1  = LE_ * FE_ * DE_;
    const int L_ef2  = LE_ * DE_ * FE_;
    const int L_e2d  = DD_ * DE_;
    const int L_dqkv = LD_ * 3 * DD_ * DD_;
    const int L_dout = LD_ * DD_ * DD_;
    const int L_df1  = LD_ * FD_ * DD_;
    const int L_df2  = LD_ * DD_ * FD_;
    short* w_eqkv = wb;
    short* w_eout = w_eqkv + L_eqkv;
    short* w_ef1  = w_eout + L_eout;
    short* w_ef2  = w_ef1 + L_ef1;
    short* w_e2d  = w_ef2 + L_ef2;
    short* w_dqkv = w_e2d + L_e2d;
    short* w_dout = w_dqkv + L_dqkv;
    short* w_df1  = w_dout + L_dout;
    short* w_df2  = w_df1 + L_df1;
    const int convTotal = L_eqkv + L_eout + L_ef1 + L_ef2 + L_e2d + L_dqkv + L_dout + L_df1 + L_df2;

    short* bx    = (short*)(ws + 12 * 1024 * 1024);
    short* qbuf  = bx   + (size_t)BS * DE_;
    short* kbuf  = qbuf + (size_t)B_ * HE_ * S_ * DH_;
    short* vtbuf = kbuf + (size_t)B_ * HE_ * S_ * DH_;
    short* battn = vtbuf + (size_t)B_ * HE_ * S_ * DH_;
    short* bt    = battn + (size_t)BS * DE_;
    short* hid   = bt + (size_t)BS * DE_;

    ConvTab tab;
    tab.src[0] = eqkv_w; tab.dst[0] = w_eqkv; tab.len[0] = L_eqkv;
    tab.src[1] = eout_w; tab.dst[1] = w_eout; tab.len[1] = L_eout;
    tab.src[2] = ef1_w;  tab.dst[2] = w_ef1;  tab.len[2] = L_ef1;
    tab.src[3] = ef2_w;  tab.dst[3] = w_ef2;  tab.len[3] = L_ef2;
    tab.src[4] = e2d_w;  tab.dst[4] = w_e2d;  tab.len[4] = L_e2d;
    tab.src[5] = dqkv_w; tab.dst[5] = w_dqkv; tab.len[5] = L_dqkv;
    tab.src[6] = dout_w; tab.dst[6] = w_dout; tab.len[6] = L_dout;
    tab.src[7] = df1_w;  tab.dst[7] = w_df1;  tab.len[7] = L_df1;
    tab.src[8] = df2_w;  tab.dst[8] = w_df2;  tab.len[8] = L_df2;
    conv_kernel<<<(convTotal + 255) / 256, 256, 0, stream>>>(tab, convTotal);

    plan_kernel<<<B_, S_, 0, stream>>>(am, pm, counts, lengths, order, visible, idx);
    enc_embed_kernel<<<BS, DE_, 0, stream>>>(ev, w_in, b_in, counts, order, bx);

    // -------------------- encoder (dead tiles skipped via counts) ----------
    for (int l = 0; l < LE_; ++l) {
        gemm_mfma<false, true><<<dim3(3 * DE_ / 64, BS / 64), 256, 0, stream>>>(
            bx, w_eqkv + (size_t)l * 3 * DE_ * DE_, eqkv_b + (size_t)l * 3 * DE_,
            nullptr, BS, 3 * DE_, DE_, qbuf, kbuf, vtbuf, HE_, DE_, counts);
        attn_flash<<<dim3(S_ / 64, HE_, B_), 256, 0, stream>>>(
            qbuf, kbuf, vtbuf, counts, counts, battn, HE_, DE_);
        gemm_mfma<false, false><<<dim3(DE_ / 64, BS / 64), 256, 0, stream>>>(
            battn, w_eout + (size_t)l * DE_ * DE_, eout_b + (size_t)l * DE_,
            bt, BS, DE_, DE_, nullptr, nullptr, nullptr, 0, 0, counts);
        add_ln_kernel<DE_><<<BS, 64, 0, stream>>>(
            bx, bt, eg1 + (size_t)l * DE_, eb1 + (size_t)l * DE_, bx, counts);
        gemm_mfma<true, false><<<dim3(FE_ / 64, BS / 64), 256, 0, stream>>>(
            bx, w_ef1 + (size_t)l * FE_ * DE_, ef1_b + (size_t)l * FE_,
            hid, BS, FE_, DE_, nullptr, nullptr, nullptr, 0, 0, counts);
        gemm_mfma<false, false><<<dim3(DE_ / 64, BS / 64), 256, 0, stream>>>(
            hid, w_ef2 + (size_t)l * DE_ * FE_, ef2_b + (size_t)l * DE_,
            bt, BS, DE_, FE_, nullptr, nullptr, nullptr, 0, 0, counts);
        add_ln_kernel<DE_><<<BS, 64, 0, stream>>>(
            bx, bt, eg2 + (size_t)l * DE_, eb2 + (size_t)l * DE_, bx, counts);
    }

    // -------------------- enc -> dec --------------------
    gemm_mfma<false, false><<<dim3(DD_ / 64, BS / 64), 256, 0, stream>>>(
        bx, w_e2d, nullptr, bt, BS, DD_, DE_, nullptr, nullptr, nullptr, 0, 0, counts);
    dec_embed_kernel<<<BS, DD_, 0, stream>>>(bt, mask_tok, visible, idx, bx);

    // -------------------- decoder (all rows live) --------------------
    for (int l = 0; l < LD_; ++l) {
        gemm_mfma<false, true><<<dim3(3 * DD_ / 64, BS / 64), 256, 0, stream>>>(
            bx, w_dqkv + (size_t)l * 3 * DD_ * DD_, dqkv_b + (size_t)l * 3 * DD_, nullptr,
            BS, 3 * DD_, DD_, qbuf, kbuf, vtbuf, HD_, DD_, nullptr);
        attn_flash<<<dim3(S_ / 64, HD_, B_), 256, 0, stream>>>(
            qbuf, kbuf, vtbuf, lengths, nullptr, battn, HD_, DD_);
        gemm_mfma<false, false><<<dim3(DD_ / 64, BS / 64), 256, 0, stream>>>(
            battn, w_dout + (size_t)l * DD_ * DD_, dout_b + (size_t)l * DD_,
            bt, BS, DD_, DD_, nullptr, nullptr, nullptr, 0, 0, nullptr);
        add_ln_kernel<DD_><<<BS, 64, 0, stream>>>(
            bx, bt, dg1 + (size_t)l * DD_, db1 + (size_t)l * DD_, bx, nullptr);
        gemm_mfma<true, false><<<dim3(FD_ / 64, BS / 64), 256, 0, stream>>>(
            bx, w_df1 + (size_t)l * FD_ * DD_, df1_b + (size_t)l * FD_,
            hid, BS, FD_, DD_, nullptr, nullptr, nullptr, 0, 0, nullptr);
        gemm_mfma<false, false><<<dim3(DD_ / 64, BS / 64), 256, 0, stream>>>(
            hid, w_df2 + (size_t)l * DD_ * FD_, df2_b + (size_t)l * DD_,
            bt, BS, DD_, FD_, nullptr, nullptr, nullptr, 0, 0, nullptr);
        if (l < LD_ - 1) {
            add_ln_kernel<DD_><<<BS, 64, 0, stream>>>(
                bx, bt, dg2 + (size_t)l * DD_, db2 + (size_t)l * DD_, bx, nullptr);
        } else {
            add_ln_head_kernel<<<BS, 64, 0, stream>>>(
                bx, bt, dg2 + (size_t)l * DD_, db2 + (size_t)l * DD_,
                qh_w, qh_b, dth_w, dth_b, out);
        }
    }
}

// Round 15
// 844.331 us; speedup vs baseline: 1.2608x; 1.0669x over previous
//
#include <hip/hip_runtime.h>
#include <hip/hip_bf16.h>

#define B_ 32
#define S_ 512
#define IN_ 19
#define DE_ 256
#define DD_ 128
#define HE_ 8
#define HD_ 4
#define LE_ 6
#define LD_ 2
#define FE_ 1024
#define FD_ 512
#define DH_ 32

typedef __attribute__((ext_vector_type(8))) short short8;
typedef __attribute__((ext_vector_type(4))) float f32x4;

__device__ __forceinline__ short f2bf(float f) {
    union { float f; unsigned u; } x; x.f = f;
    unsigned r = x.u + 0x7fff + ((x.u >> 16) & 1);
    return (short)(r >> 16);
}
__device__ __forceinline__ float bf2f(short s) {
    union { unsigned u; float f; } x; x.u = ((unsigned)(unsigned short)s) << 16;
    return x.f;
}

#define GLL16(g, l) __builtin_amdgcn_global_load_lds( \
    (const __attribute__((address_space(1))) void*)(g), \
    (__attribute__((address_space(3))) void*)(l), 16, 0, 0)

// (1/sqrt(32)) * log2(e), folded into Q at the QKV epilogue
#define QSCALE 0.2550653169f

// ---------------------------------------------------------------------------
// merged conv (weight fp32->bf16) + plan: blocks <32 plan, >=32 conv.
// ---------------------------------------------------------------------------
#define NCONV 9
struct ConvTab {
    const float* src[NCONV];
    short* dst[NCONV];
    int len[NCONV];
};
__global__ __launch_bounds__(S_) void conv_plan_kernel(
    ConvTab tab, int total,
    const int* __restrict__ am, const int* __restrict__ pm,
    int* __restrict__ counts, int* __restrict__ lengths, int* __restrict__ order,
    int* __restrict__ visible, int* __restrict__ idx) {
    if (blockIdx.x < B_) {
        int b = blockIdx.x, s = threadIdx.x;
        __shared__ int sc[S_];
        int a = (am[b * S_ + s] != 0);
        int v = a && (pm[b * S_ + s] == 0);
        visible[b * S_ + s] = v;
        sc[s] = v | (a << 16);
        __syncthreads();
#pragma unroll
        for (int off = 1; off < S_; off <<= 1) {
            int t = (s >= off) ? sc[s - off] : 0;
            __syncthreads();
            sc[s] += t;
            __syncthreads();
        }
        int incl = sc[s] & 0xffff;
        int tot = sc[S_ - 1];
        int total2 = tot & 0xffff;
        if (s == 0) { counts[b] = total2; lengths[b] = tot >> 16; }
        idx[b * S_ + s] = (incl > 0) ? incl - 1 : 0;
        if (v) order[b * S_ + incl - 1] = s;
        else   order[b * S_ + total2 + (s - incl)] = s;
    } else {
        int i = (blockIdx.x - B_) * S_ + threadIdx.x;
        if (i >= total) return;
        int j = i;
        for (int e = 0; e < NCONV; ++e) {
            if (j < tab.len[e]) { tab.dst[e][j] = f2bf(tab.src[e][j]); return; }
            j -= tab.len[e];
        }
    }
}

// ---------------------------------------------------------------------------
// encoder embed
// ---------------------------------------------------------------------------
__global__ __launch_bounds__(DE_) void enc_embed_kernel(
    const float* __restrict__ ev, const float* __restrict__ w, const float* __restrict__ bias,
    const int* __restrict__ counts, const int* __restrict__ order, short* __restrict__ out) {
    int bs = blockIdx.x;
    int b = bs / S_, s = bs % S_;
    int d = threadIdx.x;
    __shared__ float e[IN_];
    bool padded = (s >= counts[b]);
    int src = order[bs];
    if (threadIdx.x < IN_)
        e[threadIdx.x] = padded ? 0.f : ev[(size_t)(b * S_ + src) * IN_ + threadIdx.x];
    __syncthreads();
    float acc = bias[d];
#pragma unroll
    for (int i = 0; i < IN_; ++i) acc += e[i] * w[d * IN_ + i];
    out[(size_t)bs * DE_ + d] = padded ? f2bf(0.f) : f2bf(acc);
}

// ---------------------------------------------------------------------------
// MFMA bf16 GEMM, TMxTN tile, BK=32, GLL16 staging (round-12 proven layout).
// TM,TN in {64,32} (TM+TN multiple of 64). Waves 2x2 over (TM/2, TN/2).
// 32x32 variant gives 4x block count for the thin-N stages (proj/f2/e2d)
// that run at <=1 live block/CU with 64x64. k-ascending -> bit-identical.
// live: dead-encoder-tile skip.
// ---------------------------------------------------------------------------
template <int TM, int TN, bool RELU, bool QKV>
__global__ __launch_bounds__(256) void gemm_mfma(
    const short* __restrict__ A, const short* __restrict__ Wt, const float* __restrict__ bias,
    short* __restrict__ C, int M, int N, int K,
    short* __restrict__ qb, short* __restrict__ kb, short* __restrict__ vtb, int H, int D,
    const int* __restrict__ live) {
    constexpr int HM = TM / 2, HN = TN / 2;
    constexpr int MI = HM / 16, NI = HN / 16;
    constexpr int NCHA = TM / 16, NCH = (TM + TN) / 16;   // 16-row staging chunks
    int bm = blockIdx.y * TM, bn = blockIdx.x * TN;
    if (live && (bm & (S_ - 1)) >= live[bm >> 9]) return;   // dead encoder tile
    __shared__ short As[TM][32];
    __shared__ short Bs[TN][32];
    int t = threadIdx.x;
    int wave = t >> 6, lane = t & 63;
    int wm = (wave >> 1) * HM, wn = (wave & 1) * HN;
    int c = lane & 15, quad = lane >> 4;
    f32x4 acc[MI][NI];
#pragma unroll
    for (int i = 0; i < MI; ++i)
#pragma unroll
        for (int j = 0; j < NI; ++j) acc[i][j] = (f32x4){0.f, 0.f, 0.f, 0.f};

    int srow = lane >> 2, scol = (lane & 3) * 8;

    for (int k0 = 0; k0 < K; k0 += 32) {
#pragma unroll
        for (int ch0 = 0; ch0 < NCH; ch0 += 4) {
            int ch = ch0 + wave;                 // NCH % 4 == 0 -> always valid
            if (ch < NCHA)
                GLL16(A + (size_t)(bm + ch * 16 + srow) * K + k0 + scol, &As[ch * 16][0]);
            else
                GLL16(Wt + (size_t)(bn + (ch - NCHA) * 16 + srow) * K + k0 + scol,
                      &Bs[(ch - NCHA) * 16][0]);
        }
        __syncthreads();
        short8 av[MI], bv[NI];
#pragma unroll
        for (int mi = 0; mi < MI; ++mi) av[mi] = *(const short8*)&As[wm + mi * 16 + c][quad * 8];
#pragma unroll
        for (int ni = 0; ni < NI; ++ni) bv[ni] = *(const short8*)&Bs[wn + ni * 16 + c][quad * 8];
#pragma unroll
        for (int mi = 0; mi < MI; ++mi)
#pragma unroll
            for (int ni = 0; ni < NI; ++ni)
                acc[mi][ni] = __builtin_amdgcn_mfma_f32_16x16x32_bf16(av[mi], bv[ni], acc[mi][ni], 0, 0, 0);
        __syncthreads();
    }
#pragma unroll
    for (int mi = 0; mi < MI; ++mi)
#pragma unroll
        for (int ni = 0; ni < NI; ++ni)
#pragma unroll
            for (int r = 0; r < 4; ++r) {
                int R = bm + wm + mi * 16 + quad * 4 + r;
                int Ncol = bn + wn + ni * 16 + c;
                float v = acc[mi][ni][r] + (bias ? bias[Ncol] : 0.f);
                if (RELU) v = fmaxf(v, 0.f);
                if (!QKV) {
                    C[(size_t)R * N + Ncol] = f2bf(v);
                } else {
                    int s = R & (S_ - 1), b2 = R >> 9;
                    if (Ncol < D) {
                        int h = Ncol >> 5, d = Ncol & 31;
                        qb[(((size_t)b2 * H + h) * S_ + s) * DH_ + d] = f2bf(v * QSCALE);
                    } else if (Ncol < 2 * D) {
                        int n2 = Ncol - D, h = n2 >> 5, d = n2 & 31;
                        kb[(((size_t)b2 * H + h) * S_ + s) * DH_ + d] = f2bf(v);
                    } else {
                        int n2 = Ncol - 2 * D, h = n2 >> 5, d = n2 & 31;
                        vtb[(((size_t)b2 * H + h) * DH_ + d) * S_ + s] = f2bf(v);
                    }
                }
            }
}

// ---------------------------------------------------------------------------
// Flash MFMA attention, prefix-mask chunk skipping; optional q-tile skipping.
// ---------------------------------------------------------------------------
__global__ __launch_bounds__(256) void attn_flash(
    const short* __restrict__ qb, const short* __restrict__ kb, const short* __restrict__ vtb,
    const int* __restrict__ limit_arr, const int* __restrict__ qlim,
    short* __restrict__ o, int H, int D) {
    int b = blockIdx.z, h = blockIdx.y;
    if (qlim && (int)(blockIdx.x * 64) >= qlim[b]) return;
    int wave = threadIdx.x >> 6, lane = threadIdx.x & 63;
    int q0 = blockIdx.x * 64 + wave * 16;
    int c = lane & 15, quad = lane >> 4;
    size_t bh = (size_t)b * H + h;
    __shared__ short PtAll[4][16][132];
    short (*Pt)[132] = PtAll[wave];

    f32x4 zero = (f32x4){0.f, 0.f, 0.f, 0.f};
    short8 aq = *(const short8*)&qb[(bh * S_ + q0 + c) * DH_ + quad * 8];
    const short* kbase = kb + bh * S_ * DH_;
    const short* vbase = vtb + bh * DH_ * S_;

    int limit = limit_arr[b];
    int nchunks = (limit + 127) >> 7;

    float lrow[4] = {0.f, 0.f, 0.f, 0.f};
    f32x4 o0 = zero, o1 = zero;

    for (int kc = 0; kc < nchunks; ++kc) {
        f32x4 s[8];
#pragma unroll
        for (int nt = 0; nt < 8; ++nt) {
            short8 bk = *(const short8*)&kbase[(size_t)(kc * 128 + nt * 16 + c) * DH_ + quad * 8];
            s[nt] = __builtin_amdgcn_mfma_f32_16x16x32_bf16(aq, bk, zero, 0, 0, 0);
        }
#pragma unroll
        for (int nt = 0; nt < 8; ++nt) {
            bool ok = (kc * 128 + nt * 16 + c) < limit;
#pragma unroll
            for (int r = 0; r < 4; ++r) {
                float p = ok ? exp2f(s[nt][r]) : 0.f;
                s[nt][r] = p;
                lrow[r] += p;
            }
        }
#pragma unroll
        for (int nt = 0; nt < 8; ++nt)
#pragma unroll
            for (int r = 0; r < 4; ++r)
                Pt[quad * 4 + r][nt * 16 + c] = f2bf(s[nt][r]);
        // no barrier: Pt is wave-private, intra-wave ds ordering via lgkmcnt
#pragma unroll
        for (int kk = 0; kk < 4; ++kk) {
            short8 ap = *(const short8*)&Pt[c][kk * 32 + quad * 8];
            short8 b0 = *(const short8*)&vbase[(size_t)c * S_ + kc * 128 + kk * 32 + quad * 8];
            short8 b1 = *(const short8*)&vbase[(size_t)(16 + c) * S_ + kc * 128 + kk * 32 + quad * 8];
            o0 = __builtin_amdgcn_mfma_f32_16x16x32_bf16(ap, b0, o0, 0, 0, 0);
            o1 = __builtin_amdgcn_mfma_f32_16x16x32_bf16(ap, b1, o1, 0, 0, 0);
        }
    }
#pragma unroll
    for (int r = 0; r < 4; ++r) {
        float l = lrow[r];
        l += __shfl_xor(l, 1);
        l += __shfl_xor(l, 2);
        l += __shfl_xor(l, 4);
        l += __shfl_xor(l, 8);
        float inv = 1.f / l;
        int row = quad * 4 + r;
        size_t base = (size_t)(b * S_ + q0 + row) * D + h * DH_;
        o[base + c] = f2bf(o0[r] * inv);
        o[base + 16 + c] = f2bf(o1[r] * inv);
    }
}

// ---------------------------------------------------------------------------
// out = LN(x + h) * g + b — one WAVE per row; optional dead-row skip
// ---------------------------------------------------------------------------
template <int D>
__global__ __launch_bounds__(64) void add_ln_kernel(
    const short* __restrict__ x, const short* __restrict__ h,
    const float* __restrict__ g, const float* __restrict__ be,
    short* __restrict__ out, const int* __restrict__ live) {
    constexpr int E = D / 64;
    int row = blockIdx.x, t = threadIdx.x;
    if (live && (row & (S_ - 1)) >= live[row >> 9]) return;
    const short* px = x + (size_t)row * D + t * E;
    const short* ph = h + (size_t)row * D + t * E;
    float v[E];
    float s = 0.f;
#pragma unroll
    for (int e = 0; e < E; ++e) {
        v[e] = bf2f(px[e]) + bf2f(ph[e]);
        s += v[e];
    }
#pragma unroll
    for (int off = 32; off; off >>= 1) s += __shfl_xor(s, off, 64);
    float m = s / D;
    float s2 = 0.f;
#pragma unroll
    for (int e = 0; e < E; ++e) {
        float d = v[e] - m;
        s2 += d * d;
    }
#pragma unroll
    for (int off = 32; off; off >>= 1) s2 += __shfl_xor(s2, off, 64);
    float rstd = rsqrtf(s2 / D + 1e-5f);
    short* po = out + (size_t)row * D + t * E;
#pragma unroll
    for (int e = 0; e < E; ++e)
        po[e] = f2bf((v[e] - m) * rstd * g[t * E + e] + be[t * E + e]);
}

// ---------------------------------------------------------------------------
// final decoder add_ln + heads fused (D = 128, one wave per row)
// ---------------------------------------------------------------------------
__global__ __launch_bounds__(64) void add_ln_head_kernel(
    const short* __restrict__ x, const short* __restrict__ h,
    const float* __restrict__ g, const float* __restrict__ be,
    const float* __restrict__ qw, const float* __restrict__ qb,
    const float* __restrict__ dw, const float* __restrict__ db,
    float* __restrict__ out) {
    int row = blockIdx.x, t = threadIdx.x;
    int d0 = t * 2, d1 = t * 2 + 1;
    float v0 = bf2f(x[(size_t)row * DD_ + d0]) + bf2f(h[(size_t)row * DD_ + d0]);
    float v1 = bf2f(x[(size_t)row * DD_ + d1]) + bf2f(h[(size_t)row * DD_ + d1]);
    float s = v0 + v1;
#pragma unroll
    for (int off = 32; off; off >>= 1) s += __shfl_xor(s, off, 64);
    float m = s / DD_;
    float a0 = v0 - m, a1 = v1 - m;
    float s2 = a0 * a0 + a1 * a1;
#pragma unroll
    for (int off = 32; off; off >>= 1) s2 += __shfl_xor(s2, off, 64);
    float rstd = rsqrtf(s2 / DD_ + 1e-5f);
    float o0 = a0 * rstd * g[d0] + be[d0];
    float o1 = a1 * rstd * g[d1] + be[d1];
    float q = o0 * qw[d0] + o1 * qw[d1];
    float dt = o0 * dw[d0] + o1 * dw[d1];
#pragma unroll
    for (int off = 32; off; off >>= 1) {
        q += __shfl_xor(q, off, 64);
        dt += __shfl_xor(dt, off, 64);
    }
    if (t == 0) {
        out[(size_t)row * 2 + 0] = q + qb[0];
        out[(size_t)row * 2 + 1] = dt + db[0];
    }
}

// ---------------------------------------------------------------------------
// decoder embed
// ---------------------------------------------------------------------------
__global__ __launch_bounds__(DD_) void dec_embed_kernel(
    const short* __restrict__ dec_vis, const float* __restrict__ mask_token,
    const int* __restrict__ visible, const int* __restrict__ idx, short* __restrict__ out) {
    int bs = blockIdx.x, d = threadIdx.x;
    int b = bs / S_;
    short val = visible[bs] ? dec_vis[(size_t)(b * S_ + idx[bs]) * DD_ + d]
                            : f2bf(mask_token[d]);
    out[(size_t)bs * DD_ + d] = val;
}

// ---------------------------------------------------------------------------
extern "C" void kernel_launch(void* const* d_in, const int* in_sizes, int n_in,
                              void* d_out, int out_size, void* d_ws, size_t ws_size,
                              hipStream_t stream) {
    const float* ev      = (const float*)d_in[0];
    const int*  am       = (const int*)d_in[1];
    const int*  pm       = (const int*)d_in[2];
    const float* w_in    = (const float*)d_in[3];
    const float* b_in    = (const float*)d_in[4];
    const float* eqkv_w  = (const float*)d_in[5];
    const float* eqkv_b  = (const float*)d_in[6];
    const float* eout_w  = (const float*)d_in[7];
    const float* eout_b  = (const float*)d_in[8];
    const float* ef1_w   = (const float*)d_in[9];
    const float* ef1_b   = (const float*)d_in[10];
    const float* ef2_w   = (const float*)d_in[11];
    const float* ef2_b   = (const float*)d_in[12];
    const float* eg1     = (const float*)d_in[13];
    const float* eb1     = (const float*)d_in[14];
    const float* eg2     = (const float*)d_in[15];
    const float* eb2     = (const float*)d_in[16];
    const float* mask_tok= (const float*)d_in[17];
    const float* e2d_w   = (const float*)d_in[18];
    const float* dqkv_w  = (const float*)d_in[19];
    const float* dqkv_b  = (const float*)d_in[20];
    const float* dout_w  = (const float*)d_in[21];
    const float* dout_b  = (const float*)d_in[22];
    const float* df1_w   = (const float*)d_in[23];
    const float* df1_b   = (const float*)d_in[24];
    const float* df2_w   = (const float*)d_in[25];
    const float* df2_b   = (const float*)d_in[26];
    const float* dg1     = (const float*)d_in[27];
    const float* db1     = (const float*)d_in[28];
    const float* dg2     = (const float*)d_in[29];
    const float* db2     = (const float*)d_in[30];
    const float* qh_w    = (const float*)d_in[31];
    const float* qh_b    = (const float*)d_in[32];
    const float* dth_w   = (const float*)d_in[33];
    const float* dth_b   = (const float*)d_in[34];
    float* out = (float*)d_out;

    const int BS = B_ * S_;
    char* ws = (char*)d_ws;
    int* counts  = (int*)ws;
    int* lengths = counts + 32;
    int* order   = lengths + 32;
    int* visible = order + BS;
    int* idx     = visible + BS;

    short* wb = (short*)(ws + 256 * 1024);
    const int L_eqkv = LE_ * 3 * DE_ * DE_;
    const int L_eout = LE_ * DE_ * DE_;
    const int L_ef1  = LE_ * FE_ * DE_;
    const int L_ef2  = LE_ * DE_ * FE_;
    const int L_e2d  = DD_ * DE_;
    const int L_dqkv = LD_ * 3 * DD_ * DD_;
    const int L_dout = LD_ * DD_ * DD_;
    const int L_df1  = LD_ * FD_ * DD_;
    const int L_df2  = LD_ * DD_ * FD_;
    short* w_eqkv = wb;
    short* w_eout = w_eqkv + L_eqkv;
    short* w_ef1  = w_eout + L_eout;
    short* w_ef2  = w_ef1 + L_ef1;
    short* w_e2d  = w_ef2 + L_ef2;
    short* w_dqkv = w_e2d + L_e2d;
    short* w_dout = w_dqkv + L_dqkv;
    short* w_df1  = w_dout + L_dout;
    short* w_df2  = w_df1 + L_df1;
    const int convTotal = L_eqkv + L_eout + L_ef1 + L_ef2 + L_e2d + L_dqkv + L_dout + L_df1 + L_df2;

    short* bx    = (short*)(ws + 12 * 1024 * 1024);
    short* qbuf  = bx   + (size_t)BS * DE_;
    short* kbuf  = qbuf + (size_t)B_ * HE_ * S_ * DH_;
    short* vtbuf = kbuf + (size_t)B_ * HE_ * S_ * DH_;
    short* battn = vtbuf + (size_t)B_ * HE_ * S_ * DH_;
    short* bt    = battn + (size_t)BS * DE_;
    short* hid   = bt + (size_t)BS * DE_;

    ConvTab tab;
    tab.src[0] = eqkv_w; tab.dst[0] = w_eqkv; tab.len[0] = L_eqkv;
    tab.src[1] = eout_w; tab.dst[1] = w_eout; tab.len[1] = L_eout;
    tab.src[2] = ef1_w;  tab.dst[2] = w_ef1;  tab.len[2] = L_ef1;
    tab.src[3] = ef2_w;  tab.dst[3] = w_ef2;  tab.len[3] = L_ef2;
    tab.src[4] = e2d_w;  tab.dst[4] = w_e2d;  tab.len[4] = L_e2d;
    tab.src[5] = dqkv_w; tab.dst[5] = w_dqkv; tab.len[5] = L_dqkv;
    tab.src[6] = dout_w; tab.dst[6] = w_dout; tab.len[6] = L_dout;
    tab.src[7] = df1_w;  tab.dst[7] = w_df1;  tab.len[7] = L_df1;
    tab.src[8] = df2_w;  tab.dst[8] = w_df2;  tab.len[8] = L_df2;
    conv_plan_kernel<<<B_ + (convTotal + S_ - 1) / S_, S_, 0, stream>>>(
        tab, convTotal, am, pm, counts, lengths, order, visible, idx);
    enc_embed_kernel<<<BS, DE_, 0, stream>>>(ev, w_in, b_in, counts, order, bx);

    // -------------------- encoder (dead tiles skipped via counts) ----------
    for (int l = 0; l < LE_; ++l) {
        gemm_mfma<64, 64, false, true><<<dim3(3 * DE_ / 64, BS / 64), 256, 0, stream>>>(
            bx, w_eqkv + (size_t)l * 3 * DE_ * DE_, eqkv_b + (size_t)l * 3 * DE_,
            nullptr, BS, 3 * DE_, DE_, qbuf, kbuf, vtbuf, HE_, DE_, counts);
        attn_flash<<<dim3(S_ / 64, HE_, B_), 256, 0, stream>>>(
            qbuf, kbuf, vtbuf, counts, counts, battn, HE_, DE_);
        gemm_mfma<32, 32, false, false><<<dim3(DE_ / 32, BS / 32), 256, 0, stream>>>(
            battn, w_eout + (size_t)l * DE_ * DE_, eout_b + (size_t)l * DE_,
            bt, BS, DE_, DE_, nullptr, nullptr, nullptr, 0, 0, counts);
        add_ln_kernel<DE_><<<BS, 64, 0, stream>>>(
            bx, bt, eg1 + (size_t)l * DE_, eb1 + (size_t)l * DE_, bx, counts);
        gemm_mfma<64, 64, true, false><<<dim3(FE_ / 64, BS / 64), 256, 0, stream>>>(
            bx, w_ef1 + (size_t)l * FE_ * DE_, ef1_b + (size_t)l * FE_,
            hid, BS, FE_, DE_, nullptr, nullptr, nullptr, 0, 0, counts);
        gemm_mfma<32, 32, false, false><<<dim3(DE_ / 32, BS / 32), 256, 0, stream>>>(
            hid, w_ef2 + (size_t)l * DE_ * FE_, ef2_b + (size_t)l * DE_,
            bt, BS, DE_, FE_, nullptr, nullptr, nullptr, 0, 0, counts);
        add_ln_kernel<DE_><<<BS, 64, 0, stream>>>(
            bx, bt, eg2 + (size_t)l * DE_, eb2 + (size_t)l * DE_, bx, counts);
    }

    // -------------------- enc -> dec --------------------
    gemm_mfma<32, 32, false, false><<<dim3(DD_ / 32, BS / 32), 256, 0, stream>>>(
        bx, w_e2d, nullptr, bt, BS, DD_, DE_, nullptr, nullptr, nullptr, 0, 0, counts);
    dec_embed_kernel<<<BS, DD_, 0, stream>>>(bt, mask_tok, visible, idx, bx);

    // -------------------- decoder (all rows live) --------------------
    for (int l = 0; l < LD_; ++l) {
        gemm_mfma<64, 64, false, true><<<dim3(3 * DD_ / 64, BS / 64), 256, 0, stream>>>(
            bx, w_dqkv + (size_t)l * 3 * DD_ * DD_, dqkv_b + (size_t)l * 3 * DD_, nullptr,
            BS, 3 * DD_, DD_, qbuf, kbuf, vtbuf, HD_, DD_, nullptr);
        attn_flash<<<dim3(S_ / 64, HD_, B_), 256, 0, stream>>>(
            qbuf, kbuf, vtbuf, lengths, nullptr, battn, HD_, DD_);
        gemm_mfma<32, 32, false, false><<<dim3(DD_ / 32, BS / 32), 256, 0, stream>>>(
            battn, w_dout + (size_t)l * DD_ * DD_, dout_b + (size_t)l * DD_,
            bt, BS, DD_, DD_, nullptr, nullptr, nullptr, 0, 0, nullptr);
        add_ln_kernel<DD_><<<BS, 64, 0, stream>>>(
            bx, bt, dg1 + (size_t)l * DD_, db1 + (size_t)l * DD_, bx, nullptr);
        gemm_mfma<64, 64, true, false><<<dim3(FD_ / 64, BS / 64), 256, 0, stream>>>(
            bx, w_df1 + (size_t)l * FD_ * DD_, df1_b + (size_t)l * FD_,
            hid, BS, FD_, DD_, nullptr, nullptr, nullptr, 0, 0, nullptr);
        gemm_mfma<32, 32, false, false><<<dim3(DD_ / 32, BS / 32), 256, 0, stream>>>(
            hid, w_df2 + (size_t)l * DD_ * FD_, df2_b + (size_t)l * DD_,
            bt, BS, DD_, FD_, nullptr, nullptr, nullptr, 0, 0, nullptr);
        if (l < LD_ - 1) {
            add_ln_kernel<DD_><<<BS, 64, 0, stream>>>(
                bx, bt, dg2 + (size_t)l * DD_, db2 + (size_t)l * DD_, bx, nullptr);
        } else {
            add_ln_head_kernel<<<BS, 64, 0, stream>>>(
                bx, bt, dg2 + (size_t)l * DD_, db2 + (size_t)l * DD_,
                qh_w, qh_b, dth_w, dth_b, out);
        }
    }
}